// Round 6
// baseline (11674.207 us; speedup 1.0000x reference)
//
#include <hip/hip_runtime.h>
#include <hip/hip_bf16.h>

// TriangleAttention: S=256, H=4, DH=32, D=128.
// ALL tensors fp32 (reference dtype).  Round-6: round-4/5 audited scalar
// pipeline with fp32 d_out (root cause of rounds 0-5: output dtype misread).
//   [sniff]       -> dtype flag (belt-and-braces; expect 1 = fp32)
//   [ln_biasmask] -> bm fp32 [H][S][S] (bias + attn_mask), 1 MB
//   per strip of R b-rows:
//     [proj]  LN(x) @ {Wq,Wk,Wv,Wg}^T -> strip bf16 [R*256][512] (q|k|v|g)
//     [attn]  online-softmax per (b,h,q-thread), gated -> d_out (fp32)
//   [outproj]  d_out @ Wo^T -> d_out (fp32, in-place, block-row local)
#define S_DIM 256
#define D_DIM 128
#define H_DIM 4
#define NPOS  (S_DIM * S_DIM)   // 65536

__device__ __forceinline__ float b2f(unsigned short u) {
    union { float f; unsigned int u32; } c; c.u32 = ((unsigned int)u) << 16; return c.f;
}
__device__ __forceinline__ unsigned short f2b(float f) {
    __hip_bfloat16 h = __float2bfloat16(f);   // RNE
    return *reinterpret_cast<unsigned short*>(&h);
}
// Dual-dtype input read: isf=1 -> fp32 storage, else bf16 storage.
__device__ __forceinline__ float ld_in(const void* p, long i, int isf) {
    return isf ? ((const float*)p)[i] : b2f(((const unsigned short*)p)[i]);
}
// ln_w=ones, ln_b=zeros: if first dword of "lnw" is 0, pointers are swapped.
__device__ __forceinline__ void fix_ln(const void*& lnw, const void*& lnb) {
    if (*(const unsigned int*)lnw == 0u) { const void* t = lnw; lnw = lnb; lnb = t; }
}

// ---------------------------------------------------------------------------
// K1: input dtype sniff on x.  bf16-interpret first 4096 u16; exponent field
// >= 0xF0 impossible for bf16 N(0,1) data, ~certain among fp32 mantissa halves.
// ---------------------------------------------------------------------------
__global__ __launch_bounds__(256) void sniff_kernel(const unsigned short* x, int* flag)
{
    __shared__ int bad;
    if (threadIdx.x == 0) bad = 0;
    __syncthreads();
    int my = 0;
    for (int i = threadIdx.x; i < 4096; i += 256) {
        int e = (x[i] >> 7) & 0xFF;
        if (e >= 0xF0) my = 1;
    }
    if (my) atomicOr(&bad, 1);
    __syncthreads();
    if (threadIdx.x == 0) *flag = bad;   // 1 => fp32 storage
}

// ---------------------------------------------------------------------------
// K2: LayerNorm (fp32) + triangle-bias projection + attn_mask.
// One wave per position p = q*256+k; 2 elems/lane.  bm fp32 [H][NPOS].
// bias[h][q][k] = LN(x)[q,k,:] . Wb[h,:]  (b-independent) + mask[q,k].
// ---------------------------------------------------------------------------
__global__ __launch_bounds__(256) void ln_biasmask_kernel(
    const void* __restrict__ x, const void* __restrict__ mask,
    const void* lnw_, const void* lnb_,
    const void* __restrict__ Wb, const int* __restrict__ flag,
    float* __restrict__ bm)
{
    const int isf = *flag;
    const void* lnw = lnw_; const void* lnb = lnb_;
    fix_ln(lnw, lnb);
    const int wave = threadIdx.x >> 6, lane = threadIdx.x & 63;
    const int p = blockIdx.x * 4 + wave;

    float v0 = ld_in(x, (long)p * 128 + lane * 2,     isf);
    float v1 = ld_in(x, (long)p * 128 + lane * 2 + 1, isf);
    float s = v0 + v1, ss = v0 * v0 + v1 * v1;
    #pragma unroll
    for (int m = 1; m < 64; m <<= 1) { s += __shfl_xor(s, m); ss += __shfl_xor(ss, m); }
    float mean = s * (1.f / 128.f);
    float var  = ss * (1.f / 128.f) - mean * mean;
    float rstd = rsqrtf(var + 1e-5f);

    float xn0 = (v0 - mean) * rstd * ld_in(lnw, lane * 2,     isf) + ld_in(lnb, lane * 2,     isf);
    float xn1 = (v1 - mean) * rstd * ld_in(lnw, lane * 2 + 1, isf) + ld_in(lnb, lane * 2 + 1, isf);

    float mval = ld_in(mask, p, isf);
    #pragma unroll
    for (int h = 0; h < H_DIM; h++) {
        float d = xn0 * ld_in(Wb, h * 128 + lane * 2,     isf)
                + xn1 * ld_in(Wb, h * 128 + lane * 2 + 1, isf);
        #pragma unroll
        for (int m = 1; m < 64; m <<= 1) d += __shfl_xor(d, m);
        if (lane == 0) bm[(long)h * NPOS + p] = d + mval;
    }
}

// ---------------------------------------------------------------------------
// K3: scalar projection with fused LayerNorm.  One block per position p.
// strip[p_local][ef] = sum_d LN(x)[p][d] * W_c[e][d], ef = c*128+e,
// c: 0=q 1=k 2=v 3=g.  Head h occupies e = h*32..h*32+31.
// ---------------------------------------------------------------------------
__global__ __launch_bounds__(256) void proj_kernel(
    const void* __restrict__ x,
    const void* lnw_, const void* lnb_,
    const void* __restrict__ Wq, const void* __restrict__ Wk,
    const void* __restrict__ Wv, const void* __restrict__ Wg,
    const int* __restrict__ flag, int p0, unsigned short* __restrict__ strip)
{
    const int isf = *flag;
    const void* lnw = lnw_; const void* lnb = lnb_;
    fix_ln(lnw, lnb);
    const int t = threadIdx.x;
    const long p = (long)p0 + blockIdx.x;
    __shared__ float xn_s[128];
    __shared__ float red[8];

    float v = (t < 128) ? ld_in(x, p * 128 + t, isf) : 0.f;
    float s = v, ss = v * v;
    #pragma unroll
    for (int m = 1; m < 64; m <<= 1) { s += __shfl_xor(s, m); ss += __shfl_xor(ss, m); }
    if ((t & 63) == 0) { red[(t >> 6) * 2] = s; red[(t >> 6) * 2 + 1] = ss; }
    __syncthreads();
    float S  = red[0] + red[2] + red[4] + red[6];
    float SS = red[1] + red[3] + red[5] + red[7];
    float mean = S * (1.f / 128.f);
    float var  = SS * (1.f / 128.f) - mean * mean;
    float rstd = rsqrtf(var + 1e-5f);
    if (t < 128) xn_s[t] = (v - mean) * rstd * ld_in(lnw, t, isf) + ld_in(lnb, t, isf);
    __syncthreads();

    #pragma unroll
    for (int o = 0; o < 2; o++) {
        int ef = t + o * 256;                 // 0..511
        int c = ef >> 7, e = ef & 127;
        const void* W = (c == 0) ? Wq : (c == 1) ? Wk : (c == 2) ? Wv : Wg;
        float acc = 0.f;
        for (int d = 0; d < 128; d++) acc += xn_s[d] * ld_in(W, (long)e * 128 + d, isf);
        strip[(long)blockIdx.x * 512 + ef] = f2b(acc);
    }
}

// ---------------------------------------------------------------------------
// K4: scalar attention.  Block = (strip-local b, h); thread = one q row.
// Online softmax over k; K,V staged in LDS; sigmoid(g) gate fused.
// Writes fp32 into d_out columns [h*32, h*32+32).
// ---------------------------------------------------------------------------
__global__ __launch_bounds__(256) void attn_kernel(
    const unsigned short* __restrict__ strip, const float* __restrict__ bm,
    int b0, float* __restrict__ out)
{
    const int bl = blockIdx.x, h = blockIdx.y;
    const int q = threadIdx.x;            // 0..255
    __shared__ __align__(16) unsigned short Ks[256][40];   // 80 B row stride
    __shared__ __align__(16) unsigned short Vs[256][40];

    {   // stage K,V rows for this (b,h): each thread copies its own row (64 B)
        const uint4* srcK = (const uint4*)(strip + (long)(bl * 256 + q) * 512 + 128 + h * 32);
        const uint4* srcV = (const uint4*)(strip + (long)(bl * 256 + q) * 512 + 256 + h * 32);
        uint4* dK = (uint4*)(&Ks[q][0]);
        uint4* dV = (uint4*)(&Vs[q][0]);
        #pragma unroll
        for (int i = 0; i < 4; i++) { dK[i] = srcK[i]; dV[i] = srcV[i]; }
    }
    __syncthreads();

    float qv[32];
    #pragma unroll
    for (int d = 0; d < 32; d++)
        qv[d] = b2f(strip[(long)(bl * 256 + q) * 512 + h * 32 + d]);

    const float* bmr = bm + (long)h * NPOS + (long)q * 256;
    const float scale = 0.17677669529663687f;   // 1/sqrt(32)

    float m = -3.0e38f, l = 0.f, o[32];
    #pragma unroll
    for (int d = 0; d < 32; d++) o[d] = 0.f;

    for (int k = 0; k < 256; k++) {
        float s = 0.f;
        #pragma unroll
        for (int d = 0; d < 32; d++) s += qv[d] * b2f(Ks[k][d]);   // LDS broadcast
        s = s * scale + bmr[k];
        float mn   = fmaxf(m, s);
        float corr = __expf(m - mn);
        float pv   = __expf(s - mn);
        l = l * corr + pv;
        #pragma unroll
        for (int d = 0; d < 32; d++) o[d] = o[d] * corr + pv * b2f(Vs[k][d]);
        m = mn;
    }
    float inv = 1.f / l;
    #pragma unroll
    for (int d = 0; d < 32; d++) {
        float g  = b2f(strip[(long)(bl * 256 + q) * 512 + 384 + h * 32 + d]);
        float ov = o[d] * inv / (1.f + __expf(-g));
        out[((long)(b0 + bl) * 256 + q) * 128 + h * 32 + d] = ov;   // fp32
    }
}

// ---------------------------------------------------------------------------
// K5: scalar output projection, in-place on fp32 d_out.  Block = 2 positions.
// out[p][f] = sum_e gated[p][e] * Wo[f][e]
// ---------------------------------------------------------------------------
__global__ __launch_bounds__(256) void outproj_kernel(
    const void* __restrict__ Wo, const int* __restrict__ flag,
    float* out)
{
    const int isf = *flag;
    const int t = threadIdx.x;
    const long pbase = (long)blockIdx.x * 2;
    __shared__ float A[2][128];
    {
        int r = t >> 7, cc = t & 127;
        A[r][cc] = out[(pbase + r) * 128 + cc];
    }
    __syncthreads();
    int r = t >> 7, f = t & 127;
    float acc = 0.f;
    for (int e = 0; e < 128; e++) acc += A[r][e] * ld_in(Wo, (long)f * 128 + e, isf);
    out[(pbase + r) * 128 + f] = acc;   // fp32
}

// ---------------------------------------------------------------------------
extern "C" void kernel_launch(void* const* d_in, const int* in_sizes, int n_in,
                              void* d_out, int out_size, void* d_ws, size_t ws_size,
                              hipStream_t stream)
{
    (void)n_in; (void)out_size;
    // Inputs confirmed dict-order (round-5 probe: in_sizes[0]==8388608).
    // Keep the size-pattern guard anyway — it is free and deterministic.
    int perm[10];
    if (in_sizes[0] == 8388608) {
        int p[10] = {0,1,2,3,4,5,6,7,8,9};
        for (int i = 0; i < 10; i++) perm[i] = p[i];
    } else if (in_sizes[0] == 512) {
        int p[10] = {9,6,8,7,0,4,2,5,1,3};
        for (int i = 0; i < 10; i++) perm[i] = p[i];
    } else if (in_sizes[0] == 65536) {
        int p[10] = {9,0,2,1,3,7,5,8,4,6};
        for (int i = 0; i < 10; i++) perm[i] = p[i];
    } else {
        int p[10] = {9,8,7,6,5,4,3,2,1,0};
        for (int i = 0; i < 10; i++) perm[i] = p[i];
    }
    const void* x    = d_in[perm[0]];
    const void* mask = d_in[perm[1]];
    const void* lnw  = d_in[perm[2]];
    const void* lnb  = d_in[perm[3]];
    const void* Wb   = d_in[perm[4]];
    const void* Wq   = d_in[perm[5]];
    const void* Wk   = d_in[perm[6]];
    const void* Wv   = d_in[perm[7]];
    const void* Wg   = d_in[perm[8]];
    const void* Wo   = d_in[perm[9]];
    float* out = (float*)d_out;   // fp32 — reference output dtype

    // ws: [flag 16 B][bm 1 MB][strip R*256 pos * 512 ch * 2 B]
    const size_t head = 16;
    const size_t bmB  = (size_t)H_DIM * NPOS * sizeof(float);   // 1 MB
    int R = 256;
    while (R > 2 && head + bmB + (size_t)R * 256 * 512 * 2 > ws_size) R >>= 1;

    char* ws = (char*)d_ws;
    int*            flag  = (int*)ws;
    float*          bm    = (float*)(ws + head);
    unsigned short* strip = (unsigned short*)(ws + head + bmB);  // 16B-aligned

    sniff_kernel<<<1, 256, 0, stream>>>((const unsigned short*)x, flag);
    ln_biasmask_kernel<<<NPOS / 4, 256, 0, stream>>>(x, mask, lnw, lnb, Wb, flag, bm);
    for (int b0 = 0; b0 < S_DIM; b0 += R) {
        proj_kernel<<<R * 256, 256, 0, stream>>>(x, lnw, lnb, Wq, Wk, Wv, Wg,
                                                 flag, b0 * 256, strip);
        attn_kernel<<<dim3(R, H_DIM), 256, 0, stream>>>(strip, bm, b0, out);
    }
    outproj_kernel<<<NPOS / 2, 256, 0, stream>>>(Wo, flag, out);
}

// Round 7
// 241.316 us; speedup vs baseline: 48.3773x; 48.3773x over previous
//
#include <hip/hip_runtime.h>
#include <hip/hip_bf16.h>

// TriangleAttention: S=256, H=4, DH=32, D=128.  All tensors fp32 (confirmed
// rounds 4-6); intermediates bf16 (absmax headroom proven: 0.0039 vs 0.0176).
// Round-7: MFMA pipeline.  ws (<= 34.6 MB, proven available by round 6):
//   [ln_biasxn] -> bm fp32 [H][NPOS] (1 MB) + xn bf16 [NPOS][128] (16.8 MB)
//   for h in 0..3:
//     [proj_mfma]  xn @ [Wq|Wk|Wv|Wg](h)^T -> qkvg bf16 [NPOS][128] (16.8 MB)
//     [attn_mfma]  qkvg + bm -> gated o -> d_out[:, h*32:+32] (fp32)
//   [outproj_mfma] d_out @ Wo^T -> d_out (fp32, in-place, block-row local)
#define S_DIM 256
#define D_DIM 128
#define H_DIM 4
#define NPOS  (S_DIM * S_DIM)   // 65536

typedef __attribute__((ext_vector_type(8))) short  short8;   // 8 bf16 (4 VGPRs)
typedef __attribute__((ext_vector_type(4))) float  f32x4;

__device__ __forceinline__ float b2f(unsigned short u) {
    union { float f; unsigned int u32; } c; c.u32 = ((unsigned int)u) << 16; return c.f;
}
__device__ __forceinline__ unsigned short f2b(float f) {
    __hip_bfloat16 h = __float2bfloat16(f);   // RNE
    return *reinterpret_cast<unsigned short*>(&h);
}

// ---------------------------------------------------------------------------
// K1: LayerNorm (fp32) + bias projection + mask fold; also writes xn bf16.
// One wave per position p; 2 elems/lane.
// ---------------------------------------------------------------------------
__global__ __launch_bounds__(256) void ln_biasxn_kernel(
    const float* __restrict__ x, const float* __restrict__ mask,
    const float* __restrict__ lnw, const float* __restrict__ lnb,
    const float* __restrict__ Wb,
    float* __restrict__ bm, unsigned short* __restrict__ xn)
{
    const int wave = threadIdx.x >> 6, lane = threadIdx.x & 63;
    const int p = blockIdx.x * 4 + wave;

    float2 v = ((const float2*)x)[p * 64 + lane];
    float s = v.x + v.y, ss = v.x * v.x + v.y * v.y;
    #pragma unroll
    for (int m = 1; m < 64; m <<= 1) { s += __shfl_xor(s, m); ss += __shfl_xor(ss, m); }
    float mean = s * (1.f / 128.f);
    float var  = ss * (1.f / 128.f) - mean * mean;
    float rstd = rsqrtf(var + 1e-5f);

    float xn0 = (v.x - mean) * rstd * lnw[lane * 2]     + lnb[lane * 2];
    float xn1 = (v.y - mean) * rstd * lnw[lane * 2 + 1] + lnb[lane * 2 + 1];
    ((unsigned int*)xn)[p * 64 + lane] =
        (unsigned int)f2b(xn0) | ((unsigned int)f2b(xn1) << 16);

    float mval = mask[p];
    #pragma unroll
    for (int h = 0; h < H_DIM; h++) {
        float d = xn0 * Wb[h * 128 + lane * 2] + xn1 * Wb[h * 128 + lane * 2 + 1];
        #pragma unroll
        for (int m = 1; m < 64; m <<= 1) d += __shfl_xor(d, m);
        if (lane == 0) bm[(long)h * NPOS + p] = d + mval;
    }
}

// ---------------------------------------------------------------------------
// K2: per-head projection GEMM (MFMA).  qkvg[p][n] = sum_d xn[p][d]*Wcat[n][d]
// Wcat rows: n<32 Wq(h), <64 Wk(h), <96 Wv(h), <128 Wg(h) — fp32, cast bf16.
// Tile 64(m) x 128(n), K=128 in 4 steps.  LDS rows padded to 136 (2-way free).
// ---------------------------------------------------------------------------
__global__ __launch_bounds__(256) void proj_mfma_kernel(
    const unsigned short* __restrict__ xn,
    const float* __restrict__ Wq, const float* __restrict__ Wk,
    const float* __restrict__ Wv, const float* __restrict__ Wg,
    int h, unsigned short* __restrict__ qkvg)
{
    __shared__ __align__(16) unsigned short A_lds[64 * 136];
    __shared__ __align__(16) unsigned short W_lds[128 * 136];
    const int tid = threadIdx.x;
    const int m0 = blockIdx.x * 64;

    const int lr = tid >> 4, c8 = (tid & 15) * 8;
    #pragma unroll
    for (int i = 0; i < 4; i++) {
        uint4 t = *(const uint4*)(xn + (size_t)(m0 + lr + i * 16) * 128 + c8);
        *(uint4*)(&A_lds[(lr + i * 16) * 136 + c8]) = t;
    }
    #pragma unroll
    for (int i = 0; i < 8; i++) {
        int wr = lr + i * 16;   // 0..127
        const float* Ws = (wr < 32) ? Wq : (wr < 64) ? Wk : (wr < 96) ? Wv : Wg;
        const float* src = Ws + (size_t)(h * 32 + (wr & 31)) * 128 + c8;
        float4 f0 = *(const float4*)(src);
        float4 f1 = *(const float4*)(src + 4);
        unsigned short pk[8] = {f2b(f0.x), f2b(f0.y), f2b(f0.z), f2b(f0.w),
                                f2b(f1.x), f2b(f1.y), f2b(f1.z), f2b(f1.w)};
        *(uint4*)(&W_lds[wr * 136 + c8]) = *(const uint4*)pk;
    }
    __syncthreads();

    const int w = tid >> 6, lane = tid & 63;
    const int l16 = lane & 15, quad = lane >> 4;
    f32x4 acc[8];
    #pragma unroll
    for (int nt = 0; nt < 8; nt++) acc[nt] = (f32x4){0.f, 0.f, 0.f, 0.f};

    #pragma unroll
    for (int k0 = 0; k0 < 128; k0 += 32) {
        short8 a = *(const short8*)(&A_lds[(w * 16 + l16) * 136 + k0 + quad * 8]);
        #pragma unroll
        for (int nt = 0; nt < 8; nt++) {
            short8 b = *(const short8*)(&W_lds[(nt * 16 + l16) * 136 + k0 + quad * 8]);
            acc[nt] = __builtin_amdgcn_mfma_f32_16x16x32_bf16(a, b, acc[nt], 0, 0, 0);
        }
    }

    #pragma unroll
    for (int nt = 0; nt < 8; nt++)
        #pragma unroll
        for (int rr = 0; rr < 4; rr++) {
            int row = m0 + w * 16 + quad * 4 + rr;
            qkvg[(size_t)row * 128 + nt * 16 + l16] = f2b(acc[nt][rr]);
        }
}

// ---------------------------------------------------------------------------
// K3: attention for head h (MFMA).  One block per b; 4 waves x 4 q-tiles.
// qkvg: [pos][128] = q|k|v|g x32.  Scores MFMA -> softmax in regs -> P via
// per-wave LDS -> PV MFMA.  Gated fp32 write to d_out[:, h*32:+32).
// ---------------------------------------------------------------------------
__global__ __launch_bounds__(256) void attn_mfma_kernel(
    const unsigned short* __restrict__ qkvg, const float* __restrict__ bm,
    int h, float* __restrict__ out)
{
    __shared__ __align__(16) unsigned short VT_lds[32 * 264];       // V^T [dh][k]
    __shared__ __align__(16) unsigned short P_lds[4 * 16 * 264];    // per-wave P
    const int b = blockIdx.x;
    const int tid = threadIdx.x;

    {   // stage V^T
        const int row = tid >> 2, chunk = (tid & 3) * 8;
        #pragma unroll
        for (int i = 0; i < 4; i++) {
            int rr = row + i * 64;
            uint4 v = *(const uint4*)(qkvg + (size_t)(b * 256 + rr) * 128 + 64 + chunk);
            unsigned short vs[8] = {
                (unsigned short)(v.x & 0xffff), (unsigned short)(v.x >> 16),
                (unsigned short)(v.y & 0xffff), (unsigned short)(v.y >> 16),
                (unsigned short)(v.z & 0xffff), (unsigned short)(v.z >> 16),
                (unsigned short)(v.w & 0xffff), (unsigned short)(v.w >> 16)};
            #pragma unroll
            for (int j = 0; j < 8; j++) VT_lds[(chunk + j) * 264 + rr] = vs[j];
        }
    }
    __syncthreads();

    const int w = tid >> 6, lane = tid & 63;
    const int l16 = lane & 15, quad = lane >> 4;
    const float* bmh = bm + (long)h * NPOS;
    unsigned short* P_w = P_lds + w * 16 * 264;
    const float scale = 0.17677669529663687f;   // 1/sqrt(32)

    #pragma unroll 1
    for (int i = 0; i < 4; i++) {
        const int q0 = (w * 4 + i) * 16;
        short8 aq = *(const short8*)(qkvg + (size_t)(b * 256 + q0 + l16) * 128 + quad * 8);

        float sc[16][4];
        #pragma unroll
        for (int nt = 0; nt < 16; nt++) {
            short8 kb = *(const short8*)(qkvg + (size_t)(b * 256 + nt * 16 + l16) * 128 + 32 + quad * 8);
            f32x4 c = (f32x4){0.f, 0.f, 0.f, 0.f};
            c = __builtin_amdgcn_mfma_f32_16x16x32_bf16(aq, kb, c, 0, 0, 0);
            #pragma unroll
            for (int rr = 0; rr < 4; rr++) {
                int row = q0 + quad * 4 + rr;
                sc[nt][rr] = c[rr] * scale + bmh[(long)row * 256 + nt * 16 + l16];
            }
        }
        float rsum[4];
        #pragma unroll
        for (int rr = 0; rr < 4; rr++) {
            float m = sc[0][rr];
            #pragma unroll
            for (int nt = 1; nt < 16; nt++) m = fmaxf(m, sc[nt][rr]);
            #pragma unroll
            for (int msk = 1; msk < 16; msk <<= 1) m = fmaxf(m, __shfl_xor(m, msk));
            float ssum = 0.f;
            #pragma unroll
            for (int nt = 0; nt < 16; nt++) {
                float pv = __expf(sc[nt][rr] - m);
                sc[nt][rr] = pv; ssum += pv;
            }
            #pragma unroll
            for (int msk = 1; msk < 16; msk <<= 1) ssum += __shfl_xor(ssum, msk);
            rsum[rr] = ssum;
        }
        #pragma unroll
        for (int nt = 0; nt < 16; nt++)
            #pragma unroll
            for (int rr = 0; rr < 4; rr++)
                P_w[(quad * 4 + rr) * 264 + nt * 16 + l16] = f2b(sc[nt][rr]);

        f32x4 oacc[2];
        oacc[0] = (f32x4){0.f, 0.f, 0.f, 0.f};
        oacc[1] = (f32x4){0.f, 0.f, 0.f, 0.f};
        #pragma unroll
        for (int kt = 0; kt < 8; kt++) {
            short8 pa = *(const short8*)(&P_w[l16 * 264 + kt * 32 + quad * 8]);
            #pragma unroll
            for (int nh = 0; nh < 2; nh++) {
                short8 vb = *(const short8*)(&VT_lds[(nh * 16 + l16) * 264 + kt * 32 + quad * 8]);
                oacc[nh] = __builtin_amdgcn_mfma_f32_16x16x32_bf16(pa, vb, oacc[nh], 0, 0, 0);
            }
        }
        #pragma unroll
        for (int rr = 0; rr < 4; rr++) {
            int row = q0 + quad * 4 + rr;
            float inv = 1.f / rsum[rr];
            #pragma unroll
            for (int nh = 0; nh < 2; nh++) {
                int cl = nh * 16 + l16;   // 0..31
                float g = b2f(qkvg[(size_t)(b * 256 + row) * 128 + 96 + cl]);
                float ov = oacc[nh][rr] * inv;
                ov = ov / (1.f + __expf(-g));
                out[((long)b * 256 + row) * 128 + h * 32 + cl] = ov;   // fp32
            }
        }
    }
}

// ---------------------------------------------------------------------------
// K4: output projection (MFMA), in-place on fp32 d_out.
// out[p][f] = sum_e gated[p][e] * Wo[f][e].  Blocks own disjoint 64-row sets:
// stage -> sync -> overwrite own rows only (aliasing-safe).
// ---------------------------------------------------------------------------
__global__ __launch_bounds__(256) void outproj_mfma_kernel(
    const float* __restrict__ Wo, float* out)
{
    __shared__ __align__(16) unsigned short A_lds[64 * 136];
    __shared__ __align__(16) unsigned short W_lds[128 * 136];
    const int tid = threadIdx.x;
    const int m0 = blockIdx.x * 64;

    const int lr = tid >> 4, c8 = (tid & 15) * 8;
    #pragma unroll
    for (int i = 0; i < 4; i++) {
        const float* src = out + (size_t)(m0 + lr + i * 16) * 128 + c8;
        float4 f0 = *(const float4*)(src);
        float4 f1 = *(const float4*)(src + 4);
        unsigned short pk[8] = {f2b(f0.x), f2b(f0.y), f2b(f0.z), f2b(f0.w),
                                f2b(f1.x), f2b(f1.y), f2b(f1.z), f2b(f1.w)};
        *(uint4*)(&A_lds[(lr + i * 16) * 136 + c8]) = *(const uint4*)pk;
    }
    #pragma unroll
    for (int i = 0; i < 8; i++) {
        const float* src = Wo + (size_t)(lr + i * 16) * 128 + c8;
        float4 f0 = *(const float4*)(src);
        float4 f1 = *(const float4*)(src + 4);
        unsigned short pk[8] = {f2b(f0.x), f2b(f0.y), f2b(f0.z), f2b(f0.w),
                                f2b(f1.x), f2b(f1.y), f2b(f1.z), f2b(f1.w)};
        *(uint4*)(&W_lds[(lr + i * 16) * 136 + c8]) = *(const uint4*)pk;
    }
    __syncthreads();

    const int w = tid >> 6, lane = tid & 63;
    const int l16 = lane & 15, quad = lane >> 4;
    f32x4 acc[8];
    #pragma unroll
    for (int nt = 0; nt < 8; nt++) acc[nt] = (f32x4){0.f, 0.f, 0.f, 0.f};

    #pragma unroll
    for (int k0 = 0; k0 < 128; k0 += 32) {
        short8 a = *(const short8*)(&A_lds[(w * 16 + l16) * 136 + k0 + quad * 8]);
        #pragma unroll
        for (int nt = 0; nt < 8; nt++) {
            short8 b = *(const short8*)(&W_lds[(nt * 16 + l16) * 136 + k0 + quad * 8]);
            acc[nt] = __builtin_amdgcn_mfma_f32_16x16x32_bf16(a, b, acc[nt], 0, 0, 0);
        }
    }

    #pragma unroll
    for (int nt = 0; nt < 8; nt++)
        #pragma unroll
        for (int rr = 0; rr < 4; rr++) {
            int row = m0 + w * 16 + quad * 4 + rr;
            out[(size_t)row * 128 + nt * 16 + l16] = acc[nt][rr];   // fp32
        }
}

// ---------------------------------------------------------------------------
extern "C" void kernel_launch(void* const* d_in, const int* in_sizes, int n_in,
                              void* d_out, int out_size, void* d_ws, size_t ws_size,
                              hipStream_t stream)
{
    (void)in_sizes; (void)n_in; (void)out_size; (void)ws_size;
    // Inputs: dict order, fp32 (confirmed rounds 4-6).
    const float* x    = (const float*)d_in[0];
    const float* mask = (const float*)d_in[1];
    const float* lnw  = (const float*)d_in[2];
    const float* lnb  = (const float*)d_in[3];
    const float* Wb   = (const float*)d_in[4];
    const float* Wq   = (const float*)d_in[5];
    const float* Wk   = (const float*)d_in[6];
    const float* Wv   = (const float*)d_in[7];
    const float* Wg   = (const float*)d_in[8];
    const float* Wo   = (const float*)d_in[9];
    float* out = (float*)d_out;   // fp32

    // ws: [bm 1 MB][xn 16.8 MB][qkvg 16.8 MB] = 34.6 MB (round 6 proved >=34.6)
    char* ws = (char*)d_ws;
    float*          bm   = (float*)ws;                                   // 1 MB
    unsigned short* xn   = (unsigned short*)(ws + 1048576);              // 16.8 MB
    unsigned short* qkvg = (unsigned short*)(ws + 1048576 + 16777216);   // 16.8 MB

    ln_biasxn_kernel<<<NPOS / 4, 256, 0, stream>>>(x, mask, lnw, lnb, Wb, bm, xn);
    for (int h = 0; h < H_DIM; h++) {
        proj_mfma_kernel<<<NPOS / 64, 256, 0, stream>>>(xn, Wq, Wk, Wv, Wg, h, qkvg);
        attn_mfma_kernel<<<S_DIM, 256, 0, stream>>>(qkvg, bm, h, out);
    }
    outproj_mfma_kernel<<<NPOS / 64, 256, 0, stream>>>(Wo, out);
}

// Round 8
// 230.373 us; speedup vs baseline: 50.6751x; 1.0475x over previous
//
#include <hip/hip_runtime.h>
#include <hip/hip_bf16.h>

// TriangleAttention: S=256, H=4, DH=32, D=128.  All tensors fp32; bf16
// intermediates (error budget proven: 0.0059 vs 0.0176 threshold).
// Round-8: de-looped heads.  4 launches (ws >= 68.2 MB; adaptive strips else):
//   [ln_biasmask] -> bm fp32 [H][S][S] (1 MB)
//   [proj_ln]     x --fused LN--> @ {Wq|Wk|Wv|Wg}^T -> qkvg bf16 [NPOS][512]
//   [attn]        grid (b, h): qkvg + bm -> gated o -> d_out (fp32)
//   [outproj]     d_out @ Wo^T -> d_out (fp32, in-place, block-row local)
#define S_DIM 256
#define D_DIM 128
#define H_DIM 4
#define NPOS  (S_DIM * S_DIM)   // 65536

typedef __attribute__((ext_vector_type(8))) short  short8;   // 8 bf16 (4 VGPRs)
typedef __attribute__((ext_vector_type(4))) float  f32x4;

__device__ __forceinline__ float b2f(unsigned short u) {
    union { float f; unsigned int u32; } c; c.u32 = ((unsigned int)u) << 16; return c.f;
}
__device__ __forceinline__ unsigned short f2b(float f) {
    __hip_bfloat16 h = __float2bfloat16(f);   // RNE
    return *reinterpret_cast<unsigned short*>(&h);
}

// ---------------------------------------------------------------------------
// K1: LayerNorm (fp32) + triangle-bias projection + attn_mask fold.
// One wave per position p = q*256+k; 2 elems/lane.  bm fp32 [H][NPOS].
// ---------------------------------------------------------------------------
__global__ __launch_bounds__(256) void ln_biasmask_kernel(
    const float* __restrict__ x, const float* __restrict__ mask,
    const float* __restrict__ lnw, const float* __restrict__ lnb,
    const float* __restrict__ Wb, float* __restrict__ bm)
{
    const int wave = threadIdx.x >> 6, lane = threadIdx.x & 63;
    const int p = blockIdx.x * 4 + wave;

    float2 v = ((const float2*)x)[p * 64 + lane];
    float s = v.x + v.y, ss = v.x * v.x + v.y * v.y;
    #pragma unroll
    for (int m = 1; m < 64; m <<= 1) { s += __shfl_xor(s, m); ss += __shfl_xor(ss, m); }
    float mean = s * (1.f / 128.f);
    float var  = ss * (1.f / 128.f) - mean * mean;
    float rstd = rsqrtf(var + 1e-5f);

    float xn0 = (v.x - mean) * rstd * lnw[lane * 2]     + lnb[lane * 2];
    float xn1 = (v.y - mean) * rstd * lnw[lane * 2 + 1] + lnb[lane * 2 + 1];

    float mval = mask[p];
    #pragma unroll
    for (int h = 0; h < H_DIM; h++) {
        float d = xn0 * Wb[h * 128 + lane * 2] + xn1 * Wb[h * 128 + lane * 2 + 1];
        #pragma unroll
        for (int m = 1; m < 64; m <<= 1) d += __shfl_xor(d, m);
        if (lane == 0) bm[(long)h * NPOS + p] = d + mval;
    }
}

// ---------------------------------------------------------------------------
// K2: projection GEMM with fused LayerNorm (MFMA).
// strip[p - p0][gy*128 + n] = sum_d LN(x)[p][d] * W_gy[n][d]
// gy: 0=Wq 1=Wk 2=Wv 3=Wg.  Tile 64(m) x 128(n); K=128 in 4 steps.
// LN computed in fp32 during staging (16 threads per row, xor-reduce).
// ---------------------------------------------------------------------------
__global__ __launch_bounds__(256) void proj_ln_kernel(
    const float* __restrict__ x,
    const float* __restrict__ lnw, const float* __restrict__ lnb,
    const float* __restrict__ Wq, const float* __restrict__ Wk,
    const float* __restrict__ Wv, const float* __restrict__ Wg,
    int p0, unsigned short* __restrict__ strip)
{
    __shared__ __align__(16) unsigned short A_lds[64 * 136];
    __shared__ __align__(16) unsigned short W_lds[128 * 136];
    const int tid = threadIdx.x;
    const int m0 = blockIdx.x * 64;          // strip-local row base
    const int gy = blockIdx.y;
    const float* W = (gy == 0) ? Wq : (gy == 1) ? Wk : (gy == 2) ? Wv : Wg;

    const int lr = tid >> 4, c8 = (tid & 15) * 8;
    // A tile: fused LN.  Row r is covered by the 16 threads with lr == r.
    #pragma unroll
    for (int i = 0; i < 4; i++) {
        int row = lr + i * 16;
        const float* src = x + (size_t)(p0 + m0 + row) * 128 + c8;
        float4 f0 = *(const float4*)(src);
        float4 f1 = *(const float4*)(src + 4);
        float s  = f0.x + f0.y + f0.z + f0.w + f1.x + f1.y + f1.z + f1.w;
        float ss = f0.x*f0.x + f0.y*f0.y + f0.z*f0.z + f0.w*f0.w
                 + f1.x*f1.x + f1.y*f1.y + f1.z*f1.z + f1.w*f1.w;
        #pragma unroll
        for (int m = 1; m < 16; m <<= 1) { s += __shfl_xor(s, m); ss += __shfl_xor(ss, m); }
        float mean = s * (1.f / 128.f);
        float var  = ss * (1.f / 128.f) - mean * mean;
        float rstd = rsqrtf(var + 1e-5f);
        float xv[8] = {f0.x, f0.y, f0.z, f0.w, f1.x, f1.y, f1.z, f1.w};
        unsigned short pk[8];
        #pragma unroll
        for (int j = 0; j < 8; j++)
            pk[j] = f2b((xv[j] - mean) * rstd * lnw[c8 + j] + lnb[c8 + j]);
        *(uint4*)(&A_lds[row * 136 + c8]) = *(const uint4*)pk;
    }
    // W tile: fp32 -> bf16
    #pragma unroll
    for (int i = 0; i < 8; i++) {
        int wr = lr + i * 16;
        const float* src = W + (size_t)wr * 128 + c8;
        float4 f0 = *(const float4*)(src);
        float4 f1 = *(const float4*)(src + 4);
        unsigned short pk[8] = {f2b(f0.x), f2b(f0.y), f2b(f0.z), f2b(f0.w),
                                f2b(f1.x), f2b(f1.y), f2b(f1.z), f2b(f1.w)};
        *(uint4*)(&W_lds[wr * 136 + c8]) = *(const uint4*)pk;
    }
    __syncthreads();

    const int w = tid >> 6, lane = tid & 63;
    const int l16 = lane & 15, quad = lane >> 4;
    f32x4 acc[8];
    #pragma unroll
    for (int nt = 0; nt < 8; nt++) acc[nt] = (f32x4){0.f, 0.f, 0.f, 0.f};

    #pragma unroll
    for (int k0 = 0; k0 < 128; k0 += 32) {
        short8 a = *(const short8*)(&A_lds[(w * 16 + l16) * 136 + k0 + quad * 8]);
        #pragma unroll
        for (int nt = 0; nt < 8; nt++) {
            short8 b = *(const short8*)(&W_lds[(nt * 16 + l16) * 136 + k0 + quad * 8]);
            acc[nt] = __builtin_amdgcn_mfma_f32_16x16x32_bf16(a, b, acc[nt], 0, 0, 0);
        }
    }

    #pragma unroll
    for (int nt = 0; nt < 8; nt++)
        #pragma unroll
        for (int rr = 0; rr < 4; rr++) {
            int row = m0 + w * 16 + quad * 4 + rr;   // strip-local
            strip[(size_t)row * 512 + gy * 128 + nt * 16 + l16] = f2b(acc[nt][rr]);
        }
}

// ---------------------------------------------------------------------------
// K3: attention (MFMA).  Block = (strip-local b, h); 4 waves x 4 q-tiles.
// strip: [pos][512] = q|k|v|g, head h at h*32 within each 128 group.
// Scores MFMA -> reg softmax -> P via per-wave LDS -> PV MFMA -> gated fp32.
// ---------------------------------------------------------------------------
__global__ __launch_bounds__(256) void attn_kernel(
    const unsigned short* __restrict__ strip, const float* __restrict__ bm,
    int b0, float* __restrict__ out)
{
    __shared__ __align__(16) unsigned short VT_lds[32 * 264];       // V^T [dh][k]
    __shared__ __align__(16) unsigned short P_lds[4 * 16 * 264];    // per-wave P
    const int bl = blockIdx.x, h = blockIdx.y;
    const int b  = b0 + bl;
    const int tid = threadIdx.x;

    {   // stage V^T
        const int row = tid >> 2, chunk = (tid & 3) * 8;
        #pragma unroll
        for (int i = 0; i < 4; i++) {
            int rr = row + i * 64;
            uint4 v = *(const uint4*)(strip + (size_t)(bl * 256 + rr) * 512 + 256 + h * 32 + chunk);
            unsigned short vs[8] = {
                (unsigned short)(v.x & 0xffff), (unsigned short)(v.x >> 16),
                (unsigned short)(v.y & 0xffff), (unsigned short)(v.y >> 16),
                (unsigned short)(v.z & 0xffff), (unsigned short)(v.z >> 16),
                (unsigned short)(v.w & 0xffff), (unsigned short)(v.w >> 16)};
            #pragma unroll
            for (int j = 0; j < 8; j++) VT_lds[(chunk + j) * 264 + rr] = vs[j];
        }
    }
    __syncthreads();

    const int w = tid >> 6, lane = tid & 63;
    const int l16 = lane & 15, quad = lane >> 4;
    const float* bmh = bm + (long)h * NPOS;
    unsigned short* P_w = P_lds + w * 16 * 264;
    const float scale = 0.17677669529663687f;   // 1/sqrt(32)

    #pragma unroll 1
    for (int i = 0; i < 4; i++) {
        const int q0 = (w * 4 + i) * 16;
        short8 aq = *(const short8*)(strip + (size_t)(bl * 256 + q0 + l16) * 512 + h * 32 + quad * 8);

        float sc[16][4];
        #pragma unroll
        for (int nt = 0; nt < 16; nt++) {
            short8 kb = *(const short8*)(strip + (size_t)(bl * 256 + nt * 16 + l16) * 512 + 128 + h * 32 + quad * 8);
            f32x4 c = (f32x4){0.f, 0.f, 0.f, 0.f};
            c = __builtin_amdgcn_mfma_f32_16x16x32_bf16(aq, kb, c, 0, 0, 0);
            #pragma unroll
            for (int rr = 0; rr < 4; rr++) {
                int row = q0 + quad * 4 + rr;   // local q (bias is b-independent)
                sc[nt][rr] = c[rr] * scale + bmh[(long)row * 256 + nt * 16 + l16];
            }
        }
        float rsum[4];
        #pragma unroll
        for (int rr = 0; rr < 4; rr++) {
            float m = sc[0][rr];
            #pragma unroll
            for (int nt = 1; nt < 16; nt++) m = fmaxf(m, sc[nt][rr]);
            #pragma unroll
            for (int msk = 1; msk < 16; msk <<= 1) m = fmaxf(m, __shfl_xor(m, msk));
            float ssum = 0.f;
            #pragma unroll
            for (int nt = 0; nt < 16; nt++) {
                float pv = __expf(sc[nt][rr] - m);
                sc[nt][rr] = pv; ssum += pv;
            }
            #pragma unroll
            for (int msk = 1; msk < 16; msk <<= 1) ssum += __shfl_xor(ssum, msk);
            rsum[rr] = ssum;
        }
        #pragma unroll
        for (int nt = 0; nt < 16; nt++)
            #pragma unroll
            for (int rr = 0; rr < 4; rr++)
                P_w[(quad * 4 + rr) * 264 + nt * 16 + l16] = f2b(sc[nt][rr]);

        f32x4 oacc[2];
        oacc[0] = (f32x4){0.f, 0.f, 0.f, 0.f};
        oacc[1] = (f32x4){0.f, 0.f, 0.f, 0.f};
        #pragma unroll
        for (int kt = 0; kt < 8; kt++) {
            short8 pa = *(const short8*)(&P_w[l16 * 264 + kt * 32 + quad * 8]);
            #pragma unroll
            for (int nh = 0; nh < 2; nh++) {
                short8 vb = *(const short8*)(&VT_lds[(nh * 16 + l16) * 264 + kt * 32 + quad * 8]);
                oacc[nh] = __builtin_amdgcn_mfma_f32_16x16x32_bf16(pa, vb, oacc[nh], 0, 0, 0);
            }
        }
        #pragma unroll
        for (int rr = 0; rr < 4; rr++) {
            int row = q0 + quad * 4 + rr;
            float inv = 1.f / rsum[rr];
            #pragma unroll
            for (int nh = 0; nh < 2; nh++) {
                int cl = nh * 16 + l16;   // 0..31
                float g = b2f(strip[(size_t)(bl * 256 + row) * 512 + 384 + h * 32 + cl]);
                float ov = oacc[nh][rr] * inv;
                ov = ov / (1.f + __expf(-g));
                out[((long)b * 256 + row) * 128 + h * 32 + cl] = ov;   // fp32
            }
        }
    }
}

// ---------------------------------------------------------------------------
// K4: output projection (MFMA), in-place on fp32 d_out.
// out[p][f] = sum_e gated[p][e] * Wo[f][e].  Blocks own disjoint 64-row sets.
// ---------------------------------------------------------------------------
__global__ __launch_bounds__(256) void outproj_mfma_kernel(
    const float* __restrict__ Wo, float* out)
{
    __shared__ __align__(16) unsigned short A_lds[64 * 136];
    __shared__ __align__(16) unsigned short W_lds[128 * 136];
    const int tid = threadIdx.x;
    const int m0 = blockIdx.x * 64;

    const int lr = tid >> 4, c8 = (tid & 15) * 8;
    #pragma unroll
    for (int i = 0; i < 4; i++) {
        const float* src = out + (size_t)(m0 + lr + i * 16) * 128 + c8;
        float4 f0 = *(const float4*)(src);
        float4 f1 = *(const float4*)(src + 4);
        unsigned short pk[8] = {f2b(f0.x), f2b(f0.y), f2b(f0.z), f2b(f0.w),
                                f2b(f1.x), f2b(f1.y), f2b(f1.z), f2b(f1.w)};
        *(uint4*)(&A_lds[(lr + i * 16) * 136 + c8]) = *(const uint4*)pk;
    }
    #pragma unroll
    for (int i = 0; i < 8; i++) {
        const float* src = Wo + (size_t)(lr + i * 16) * 128 + c8;
        float4 f0 = *(const float4*)(src);
        float4 f1 = *(const float4*)(src + 4);
        unsigned short pk[8] = {f2b(f0.x), f2b(f0.y), f2b(f0.z), f2b(f0.w),
                                f2b(f1.x), f2b(f1.y), f2b(f1.z), f2b(f1.w)};
        *(uint4*)(&W_lds[(lr + i * 16) * 136 + c8]) = *(const uint4*)pk;
    }
    __syncthreads();

    const int w = tid >> 6, lane = tid & 63;
    const int l16 = lane & 15, quad = lane >> 4;
    f32x4 acc[8];
    #pragma unroll
    for (int nt = 0; nt < 8; nt++) acc[nt] = (f32x4){0.f, 0.f, 0.f, 0.f};

    #pragma unroll
    for (int k0 = 0; k0 < 128; k0 += 32) {
        short8 a = *(const short8*)(&A_lds[(w * 16 + l16) * 136 + k0 + quad * 8]);
        #pragma unroll
        for (int nt = 0; nt < 8; nt++) {
            short8 b = *(const short8*)(&W_lds[(nt * 16 + l16) * 136 + k0 + quad * 8]);
            acc[nt] = __builtin_amdgcn_mfma_f32_16x16x32_bf16(a, b, acc[nt], 0, 0, 0);
        }
    }

    #pragma unroll
    for (int nt = 0; nt < 8; nt++)
        #pragma unroll
        for (int rr = 0; rr < 4; rr++) {
            int row = m0 + w * 16 + quad * 4 + rr;
            out[(size_t)row * 128 + nt * 16 + l16] = acc[nt][rr];   // fp32
        }
}

// ---------------------------------------------------------------------------
extern "C" void kernel_launch(void* const* d_in, const int* in_sizes, int n_in,
                              void* d_out, int out_size, void* d_ws, size_t ws_size,
                              hipStream_t stream)
{
    (void)in_sizes; (void)n_in; (void)out_size;
    const float* x    = (const float*)d_in[0];
    const float* mask = (const float*)d_in[1];
    const float* lnw  = (const float*)d_in[2];
    const float* lnb  = (const float*)d_in[3];
    const float* Wb   = (const float*)d_in[4];
    const float* Wq   = (const float*)d_in[5];
    const float* Wk   = (const float*)d_in[6];
    const float* Wv   = (const float*)d_in[7];
    const float* Wg   = (const float*)d_in[8];
    const float* Wo   = (const float*)d_in[9];
    float* out = (float*)d_out;   // fp32

    // ws: [bm 1 MB][strip HB*256*512*2 B].  HB = b-rows per strip, largest
    // power of two that fits (round-7 profile: ws ~268 MB -> HB=256, 1 strip).
    const size_t bmB = (size_t)H_DIM * NPOS * sizeof(float);   // 1 MB
    int HB = 256;
    while (HB > 16 && bmB + (size_t)HB * 256 * 512 * 2 > ws_size) HB >>= 1;

    char* ws = (char*)d_ws;
    float*          bm    = (float*)ws;
    unsigned short* strip = (unsigned short*)(ws + bmB);

    ln_biasmask_kernel<<<NPOS / 4, 256, 0, stream>>>(x, mask, lnw, lnb, Wb, bm);
    for (int b0 = 0; b0 < S_DIM; b0 += HB) {
        proj_ln_kernel<<<dim3(HB * 4, 4), 256, 0, stream>>>(
            x, lnw, lnb, Wq, Wk, Wv, Wg, b0 * 256, strip);
        attn_kernel<<<dim3(HB, H_DIM), 256, 0, stream>>>(strip, bm, b0, out);
    }
    outproj_mfma_kernel<<<NPOS / 64, 256, 0, stream>>>(Wo, out);
}